// Round 7
// baseline (210.856 us; speedup 1.0000x reference)
//
#include <hip/hip_runtime.h>
#include <hip/hip_bf16.h>
#include <stdint.h>

// Problem dims (fixed by reference setup_inputs)
#define B_SZ 128
#define R_SZ 36       // real regions per image
#define RP_SZ 48      // padded regions (dup row 35) -> multiple of 16
#define W_SZ 60       // real words per caption
#define WP_SZ 64      // padded words (dup word 59, masked in epilogue)
#define D_SZ 1024
#define MARGIN 0.2f

#define ATILE (192 * 64)   // bf16 elems per A K-tile

typedef __attribute__((ext_vector_type(8))) short short8;   // 8 bf16 (MFMA A/B frag)
typedef __attribute__((ext_vector_type(4))) float f32x4;    // MFMA C/D frag

typedef __attribute__((address_space(3))) unsigned int lds_u32;
typedef const __attribute__((address_space(1))) unsigned int glb_u32;

__device__ __forceinline__ void gload16(const unsigned short* g, unsigned short* l) {
    __builtin_amdgcn_global_load_lds((glb_u32*)g, (lds_u32*)l, 16, 0, 0);
}

__device__ __forceinline__ unsigned short f2bf(float f) {
    union { float f; uint32_t u; } x; x.f = f;
    uint32_t u = x.u;
    uint32_t r = (u + 0x7FFFu + ((u >> 16) & 1u)) >> 16;   // RNE bf16
    return (unsigned short)r;
}

// Fused fp32 -> bf16 convert + row-pad for BOTH tensors in one launch.
__global__ __launch_bounds__(256) void convert_pad_kernel(
        const float* __restrict__ im, const float* __restrict__ s,
        unsigned short* __restrict__ imb, unsigned short* __restrict__ sb) {
    const int n4_im = B_SZ * RP_SZ * D_SZ / 4;
    const int n4_s  = B_SZ * WP_SZ * D_SZ / 4;
    int i = blockIdx.x * 256 + threadIdx.x;
    const float* src;
    unsigned short* dst;
    int srcIdx;
    if (i < n4_im) {
        int idx = i * 4;
        int d  = idx & (D_SZ - 1);
        int rj = idx >> 10;
        int r  = rj % RP_SZ;
        int j  = rj / RP_SZ;
        int rs = r < R_SZ ? r : R_SZ - 1;
        src = im; dst = imb + idx;
        srcIdx = ((j * R_SZ + rs) << 10) + d;
    } else {
        int i2 = i - n4_im;
        if (i2 >= n4_s) return;
        int idx = i2 * 4;
        int d  = idx & (D_SZ - 1);
        int rj = idx >> 10;
        int r  = rj & (WP_SZ - 1);
        int j  = rj >> 6;
        int rs = r < W_SZ ? r : W_SZ - 1;
        src = s; dst = sb + idx;
        srcIdx = ((j * W_SZ + rs) << 10) + d;
    }
    const float4 v = *reinterpret_cast<const float4*>(src + srcIdx);
    ushort4 o;
    o.x = f2bf(v.x); o.y = f2bf(v.y); o.z = f2bf(v.z); o.w = f2bf(v.w);
    *reinterpret_cast<ushort4*>(dst) = o;
}

// Fused GEMM + MISA epilogue.
// Block 192x256, BK=64, 8 waves (2Mx4N), per-wave 96x64 (acc[6][4], 16x16x32).
// A staged through double-buffered LDS (48 KB) with the validated XOR
// slot-swizzle; B fragments loaded DIRECTLY from global (L2-resident) into
// registers -- halves LDS read traffic and removes B-barrier coupling.
// Per tile: 8 B-loads -> stage A(kt+1) (3 gload_lds) -> 12 A ds_reads ->
// 48 MFMAs (compiler-counted lgkm/vm waits interleave reads under MFMAs) ->
// vmcnt(0) + one s_barrier (A dbuf protection). 2 waves/SIMD.
__global__ __launch_bounds__(512, 2) void scores_kernel(
        const unsigned short* __restrict__ imb,   // [128][48][1024] bf16 (padded)
        const unsigned short* __restrict__ sb,    // [128][64][1024] bf16 (padded)
        const int* __restrict__ s_l,
        float* __restrict__ S)                    // [j][i]
{
    __shared__ unsigned short As[2 * ATILE];

    const int tid  = threadIdx.x;
    const int wid  = tid >> 6;        // 0..7
    const int lane = tid & 63;
    const int l15  = lane & 15;
    const int kgrp = lane >> 4;       // 0..3
    const int wr   = wid >> 2;        // 0..1 (M)
    const int wc   = wid & 3;         // 0..3 (N)

    // XCD-chunked swizzle over 1024 blocks (it-chunks: B panel per XCD L2)
    int bid = blockIdx.x;
    int swz = (bid & 7) * 128 + (bid >> 3);
    int jt = swz & 31;                // 0..31 (4 images each)
    int it = swz >> 5;                // 0..31 (4 captions each)

    // A staging: 8 lanes per 128B row-segment, pre-swizzled source slot
    const int lrow = lane >> 3;                   // 0..7 == row&7 of staged row
    const int slot = (lane & 7) ^ lrow;           // LDS[row][s] = G[row][s^(row&7)]

    const unsigned short* gA[3];
    int aoff[3];
#pragma unroll
    for (int c = 0; c < 3; ++c) {
        int chunk = wid + c * 8;                  // 0..23
        int row = chunk * 8 + lrow;               // 0..191
        gA[c] = imb + (size_t)(jt * 192 + row) * D_SZ + slot * 8;
        aoff[c] = chunk * 512 + lane * 8;         // linear: base + lane*16B
    }

    // A ds_read addressing: elem = row*64 + ((k2*4+kgrp)^(l15&7))*8; k2=1 -> ^32
    const int rsw = l15 & 7;
    const int k0off = (kgrp ^ rsw) * 8;
    int abase[6];
#pragma unroll
    for (int rf = 0; rf < 6; ++rf)
        abase[rf] = (wr * 96 + rf * 16 + l15) * 64 + k0off;

    // B direct-from-global row pointers: word-row = wc*64 + cf*16 + l15
    const unsigned short* gBF[4];
#pragma unroll
    for (int cf = 0; cf < 4; ++cf)
        gBF[cf] = sb + (size_t)(it * 256 + wc * 64 + cf * 16 + l15) * D_SZ + kgrp * 8;

    f32x4 acc[6][4] = {};

    // prologue: stage A tile 0 into buffer 0
#pragma unroll
    for (int c = 0; c < 3; ++c) gload16(gA[c], As + aoff[c]);
    asm volatile("s_waitcnt vmcnt(0)" ::: "memory");
    __builtin_amdgcn_s_barrier();

#pragma unroll 2
    for (int kt = 0; kt < 16; ++kt) {
        const int cur = kt & 1;
        const unsigned short* Ac = As + cur * ATILE;
        const int ko = kt * 64;

        // B fragments for tile kt straight from global (L2-hit) -- issued FIRST
        // so their in-order vmcnt retirement is not gated on the staging loads.
        short8 bfr[2][4];
#pragma unroll
        for (int k2 = 0; k2 < 2; ++k2)
#pragma unroll
            for (int cf = 0; cf < 4; ++cf)
                bfr[k2][cf] = *reinterpret_cast<const short8*>(gBF[cf] + ko + k2 * 32);

        // stage A(kt+1) into the other buffer (free since barrier of kt-1)
        if (kt < 15) {
            unsigned short* Ad = As + (cur ^ 1) * ATILE;
#pragma unroll
            for (int c = 0; c < 3; ++c) gload16(gA[c] + ko + 64, Ad + aoff[c]);
        }

        // A fragments from LDS
        short8 afr[2][6];
#pragma unroll
        for (int k2 = 0; k2 < 2; ++k2)
#pragma unroll
            for (int rf = 0; rf < 6; ++rf)
                afr[k2][rf] = *reinterpret_cast<const short8*>(Ac + (abase[rf] ^ (k2 * 32)));

        // MFMAs: no explicit lgkm/vm drain -- compiler emits counted waits so
        // early-k2 MFMAs overlap late reads and B-load returns.
        __builtin_amdgcn_s_setprio(1);
#pragma unroll
        for (int k2 = 0; k2 < 2; ++k2)
#pragma unroll
            for (int rf = 0; rf < 6; ++rf)
#pragma unroll
                for (int cf = 0; cf < 4; ++cf)
                    acc[rf][cf] = __builtin_amdgcn_mfma_f32_16x16x32_bf16(
                        afr[k2][rf], bfr[k2][cf], acc[rf][cf], 0, 0, 0);
        __builtin_amdgcn_s_setprio(0);

        if (kt < 15) {
            asm volatile("s_waitcnt vmcnt(0)" ::: "memory");  // A(kt+1) landed
            __builtin_amdgcn_s_barrier();                     // dbuf handoff
        }
    }

    // Epilogue: wave (wr,wc) owns caption i = it*4+wc, images j = jt*4 + wr*2 + {0,1}.
    // C frag layout: col = l15 (word), row = kgrp*4 + e (region).
    const int i_cap = it * 4 + wc;
    const int nw = s_l[i_cap];
    const float inv = 1.0f / (float)nw;
#pragma unroll
    for (int h = 0; h < 2; ++h) {       // image half: frags rf = h*3 .. h*3+2 (48 rows)
        float sum = 0.0f;
#pragma unroll
        for (int cf = 0; cf < 4; ++cf) {
            float m = acc[h * 3][cf][0];
#pragma unroll
            for (int rf = h * 3; rf < h * 3 + 3; ++rf)
#pragma unroll
                for (int e = 0; e < 4; ++e)
                    m = fmaxf(m, acc[rf][cf][e]);
            m = fmaxf(m, __shfl_xor(m, 16));
            m = fmaxf(m, __shfl_xor(m, 32));
            int wv = cf * 16 + l15;
            if (wv < nw) sum += m;
        }
        sum += __shfl_xor(sum, 1);
        sum += __shfl_xor(sum, 2);
        sum += __shfl_xor(sum, 4);
        sum += __shfl_xor(sum, 8);
        if (lane == 0) {
            int j_img = jt * 4 + wr * 2 + h;
            S[j_img * B_SZ + i_cap] = sum * inv;
        }
    }
}

// Contrastive loss over the 128x128 score matrix, single block
__global__ __launch_bounds__(256) void loss_kernel(
        const float* __restrict__ S, float* __restrict__ out) {
    __shared__ float diag[B_SZ];
    __shared__ float red[256];
    int t = threadIdx.x;
    if (t < B_SZ) diag[t] = S[t * (B_SZ + 1)];
    __syncthreads();
    float acc = 0.0f;
    for (int idx = t; idx < B_SZ * B_SZ; idx += 256) {
        int a = idx >> 7, b = idx & (B_SZ - 1);
        if (a != b) {
            float v = S[idx];
            acc += fmaxf(MARGIN + v - diag[a], 0.0f)
                 + fmaxf(MARGIN + v - diag[b], 0.0f);
        }
    }
    red[t] = acc;
    __syncthreads();
    for (int s = 128; s > 0; s >>= 1) {
        if (t < s) red[t] += red[t + s];
        __syncthreads();
    }
    if (t == 0) out[0] = red[0];
}

extern "C" void kernel_launch(void* const* d_in, const int* in_sizes, int n_in,
                              void* d_out, int out_size, void* d_ws, size_t ws_size,
                              hipStream_t stream) {
    const float* im  = (const float*)d_in[0];
    const float* s   = (const float*)d_in[1];
    const int*   s_l = (const int*)d_in[2];
    // d_in[3] (x) unused by the math

    const int n_im_pad = B_SZ * RP_SZ * D_SZ;   // 6,291,456
    const int n_s_pad  = B_SZ * WP_SZ * D_SZ;   // 8,388,608

    unsigned short* imb = (unsigned short*)d_ws;
    unsigned short* sb  = imb + n_im_pad;
    float* S = (float*)(sb + n_s_pad);          // 128*128 floats

    const int n4_total = (n_im_pad + n_s_pad) / 4;
    convert_pad_kernel<<<(n4_total + 255) / 256, 256, 0, stream>>>(im, s, imb, sb);

    scores_kernel<<<1024, 512, 0, stream>>>(imb, sb, s_l, S);

    loss_kernel<<<1, 256, 0, stream>>>(S, (float*)d_out);
}

// Round 8
// 129.955 us; speedup vs baseline: 1.6225x; 1.6225x over previous
//
#include <hip/hip_runtime.h>
#include <hip/hip_bf16.h>
#include <stdint.h>

// Problem dims (fixed by reference setup_inputs)
#define B_SZ 128
#define R_SZ 36       // real regions per image
#define RP_SZ 48      // padded regions (dup row 35) -> multiple of 16
#define W_SZ 60       // real words per caption
#define WP_SZ 64      // padded words (dup word 59, masked in epilogue)
#define D_SZ 1024
#define MARGIN 0.2f

#define ATILE (192 * 64)   // bf16 elems per A K-tile
#define BTILE (256 * 64)   // bf16 elems per B K-tile

typedef __attribute__((ext_vector_type(8))) short short8;   // 8 bf16 (MFMA A/B frag)
typedef __attribute__((ext_vector_type(4))) float f32x4;    // MFMA C/D frag

typedef __attribute__((address_space(3))) unsigned int lds_u32;
typedef const __attribute__((address_space(1))) unsigned int glb_u32;

__device__ __forceinline__ void gload16(const unsigned short* g, unsigned short* l) {
    __builtin_amdgcn_global_load_lds((glb_u32*)g, (lds_u32*)l, 16, 0, 0);
}

__device__ __forceinline__ unsigned short f2bf(float f) {
    union { float f; uint32_t u; } x; x.f = f;
    uint32_t u = x.u;
    uint32_t r = (u + 0x7FFFu + ((u >> 16) & 1u)) >> 16;   // RNE bf16
    return (unsigned short)r;
}

// Fused fp32 -> bf16 convert + row-pad for BOTH tensors in one launch.
__global__ __launch_bounds__(256) void convert_pad_kernel(
        const float* __restrict__ im, const float* __restrict__ s,
        unsigned short* __restrict__ imb, unsigned short* __restrict__ sb) {
    const int n4_im = B_SZ * RP_SZ * D_SZ / 4;
    const int n4_s  = B_SZ * WP_SZ * D_SZ / 4;
    int i = blockIdx.x * 256 + threadIdx.x;
    const float* src;
    unsigned short* dst;
    int srcIdx;
    if (i < n4_im) {
        int idx = i * 4;
        int d  = idx & (D_SZ - 1);
        int rj = idx >> 10;
        int r  = rj % RP_SZ;
        int j  = rj / RP_SZ;
        int rs = r < R_SZ ? r : R_SZ - 1;
        src = im; dst = imb + idx;
        srcIdx = ((j * R_SZ + rs) << 10) + d;
    } else {
        int i2 = i - n4_im;
        if (i2 >= n4_s) return;
        int idx = i2 * 4;
        int d  = idx & (D_SZ - 1);
        int rj = idx >> 10;
        int r  = rj & (WP_SZ - 1);
        int j  = rj >> 6;
        int rs = r < W_SZ ? r : W_SZ - 1;
        src = s; dst = sb + idx;
        srcIdx = ((j * W_SZ + rs) << 10) + d;
    }
    const float4 v = *reinterpret_cast<const float4*>(src + srcIdx);
    ushort4 o;
    o.x = f2bf(v.x); o.y = f2bf(v.y); o.z = f2bf(v.z); o.w = f2bf(v.w);
    *reinterpret_cast<ushort4*>(dst) = o;
}

// Fused GEMM + MISA epilogue.
// Round-4 geometry (validated): block 192x256, BK=64, 8 waves (2Mx4N),
// per-wave 96x64 (acc[6][4] of 16x16x32), A+B double-buffered LDS 112 KB,
// XOR slot-swizzle (0 bank conflicts), 2 waves/SIMD.
// Round-8 schedule: ONE window per K-tile -- issue all 20 ds_read_b128 (both
// k2 slices) -> stage kt+1 (7 gload_lds) -> 48 MFMAs with NO explicit lgkm
// drain (compiler emits counted lgkmcnt per frag: slice-0 MFMAs overlap
// slice-1 reads; wave stagger keeps LDS+MFMA pipes co-busy) -> vmcnt(0) +
// single s_barrier (dbuf handoff; read retirement implied by MFMA operands).
__global__ __launch_bounds__(512, 2) void scores_kernel(
        const unsigned short* __restrict__ imb,   // [128][48][1024] bf16 (padded)
        const unsigned short* __restrict__ sb,    // [128][64][1024] bf16 (padded)
        const int* __restrict__ s_l,
        float* __restrict__ S)                    // [j][i]
{
    __shared__ unsigned short As[2 * ATILE];
    __shared__ unsigned short Bs[2 * BTILE];

    const int tid  = threadIdx.x;
    const int wid  = tid >> 6;        // 0..7
    const int lane = tid & 63;
    const int l15  = lane & 15;
    const int kgrp = lane >> 4;       // 0..3
    const int wr   = wid >> 2;        // 0..1 (M)
    const int wc   = wid & 3;         // 0..3 (N)

    // XCD-chunked swizzle over 1024 blocks (it-chunks: B panel per XCD L2)
    int bid = blockIdx.x;
    int swz = (bid & 7) * 128 + (bid >> 3);
    int jt = swz & 31;                // 0..31 (4 images each)
    int it = swz >> 5;                // 0..31 (4 captions each)

    // staging: 8 lanes per 128B row-segment, pre-swizzled source slot
    const int lrow = lane >> 3;                   // 0..7 == row&7 of staged row
    const int slot = (lane & 7) ^ lrow;           // LDS[row][s] = G[row][s^(row&7)]

    const unsigned short* gA[3];
    int aoff[3];
#pragma unroll
    for (int c = 0; c < 3; ++c) {
        int chunk = wid + c * 8;                  // 0..23
        int row = chunk * 8 + lrow;               // 0..191
        gA[c] = imb + (size_t)(jt * 192 + row) * D_SZ + slot * 8;
        aoff[c] = chunk * 512 + lane * 8;         // linear: base + lane*16B
    }
    const unsigned short* gB[4];
    int boff[4];
#pragma unroll
    for (int c = 0; c < 4; ++c) {
        int chunk = wid + c * 8;                  // 0..31
        int row = chunk * 8 + lrow;               // 0..255
        gB[c] = sb + (size_t)(it * 256 + row) * D_SZ + slot * 8;
        boff[c] = chunk * 512 + lane * 8;
    }

    // ds_read addressing: elem = row*64 + ((k2*4+kgrp)^(l15&7))*8; k2=1 -> ^32
    const int rsw = l15 & 7;
    const int k0off = (kgrp ^ rsw) * 8;
    int abase[6];
#pragma unroll
    for (int rf = 0; rf < 6; ++rf)
        abase[rf] = (wr * 96 + rf * 16 + l15) * 64 + k0off;
    int bbase[4];
#pragma unroll
    for (int cf = 0; cf < 4; ++cf)
        bbase[cf] = (wc * 64 + cf * 16 + l15) * 64 + k0off;

    f32x4 acc[6][4] = {};

    // prologue: stage tile 0 into buffer 0
#pragma unroll
    for (int c = 0; c < 3; ++c) gload16(gA[c], As + aoff[c]);
#pragma unroll
    for (int c = 0; c < 4; ++c) gload16(gB[c], Bs + boff[c]);
    asm volatile("s_waitcnt vmcnt(0)" ::: "memory");
    __builtin_amdgcn_s_barrier();

#pragma unroll 2
    for (int kt = 0; kt < 16; ++kt) {
        const int cur = kt & 1;
        const unsigned short* Ac = As + cur * ATILE;
        const unsigned short* Bc = Bs + cur * BTILE;

        // issue ALL reads for tile kt (both k2 slices): 20 ds_read_b128
        short8 afr[2][6], bfr[2][4];
#pragma unroll
        for (int k2 = 0; k2 < 2; ++k2) {
#pragma unroll
            for (int rf = 0; rf < 6; ++rf)
                afr[k2][rf] = *reinterpret_cast<const short8*>(Ac + (abase[rf] ^ (k2 * 32)));
#pragma unroll
            for (int cf = 0; cf < 4; ++cf)
                bfr[k2][cf] = *reinterpret_cast<const short8*>(Bc + (bbase[cf] ^ (k2 * 32)));
        }

        // stage tile kt+1 into the other buffer (safe: all waves' kt-1 reads
        // retired before the end-of-kt-1 barrier)
        if (kt < 15) {
            const int ko = (kt + 1) * 64;
            unsigned short* Ad = As + (cur ^ 1) * ATILE;
            unsigned short* Bd = Bs + (cur ^ 1) * BTILE;
#pragma unroll
            for (int c = 0; c < 3; ++c) gload16(gA[c] + ko, Ad + aoff[c]);
#pragma unroll
            for (int c = 0; c < 4; ++c) gload16(gB[c] + ko, Bd + boff[c]);
        }

        // MFMAs: no explicit lgkm drain -- compiler emits counted lgkmcnt per
        // fragment dependency, overlapping slice-0 compute with slice-1 reads.
        __builtin_amdgcn_s_setprio(1);
#pragma unroll
        for (int k2 = 0; k2 < 2; ++k2)
#pragma unroll
            for (int rf = 0; rf < 6; ++rf)
#pragma unroll
                for (int cf = 0; cf < 4; ++cf)
                    acc[rf][cf] = __builtin_amdgcn_mfma_f32_16x16x32_bf16(
                        afr[k2][rf], bfr[k2][cf], acc[rf][cf], 0, 0, 0);
        __builtin_amdgcn_s_setprio(0);

        if (kt < 15) {
            asm volatile("s_waitcnt vmcnt(0)" ::: "memory");  // tile kt+1 staged
            __builtin_amdgcn_s_barrier();                     // dbuf handoff
        }
    }

    // Epilogue: wave (wr,wc) owns caption i = it*4+wc, images j = jt*4 + wr*2 + {0,1}.
    // C frag layout: col = l15 (word), row = kgrp*4 + e (region).
    const int i_cap = it * 4 + wc;
    const int nw = s_l[i_cap];
    const float inv = 1.0f / (float)nw;
#pragma unroll
    for (int h = 0; h < 2; ++h) {       // image half: frags rf = h*3 .. h*3+2 (48 rows)
        float sum = 0.0f;
#pragma unroll
        for (int cf = 0; cf < 4; ++cf) {
            float m = acc[h * 3][cf][0];
#pragma unroll
            for (int rf = h * 3; rf < h * 3 + 3; ++rf)
#pragma unroll
                for (int e = 0; e < 4; ++e)
                    m = fmaxf(m, acc[rf][cf][e]);
            m = fmaxf(m, __shfl_xor(m, 16));
            m = fmaxf(m, __shfl_xor(m, 32));
            int wv = cf * 16 + l15;
            if (wv < nw) sum += m;
        }
        sum += __shfl_xor(sum, 1);
        sum += __shfl_xor(sum, 2);
        sum += __shfl_xor(sum, 4);
        sum += __shfl_xor(sum, 8);
        if (lane == 0) {
            int j_img = jt * 4 + wr * 2 + h;
            S[j_img * B_SZ + i_cap] = sum * inv;
        }
    }
}

// Contrastive loss over the 128x128 score matrix, single block
__global__ __launch_bounds__(256) void loss_kernel(
        const float* __restrict__ S, float* __restrict__ out) {
    __shared__ float diag[B_SZ];
    __shared__ float red[256];
    int t = threadIdx.x;
    if (t < B_SZ) diag[t] = S[t * (B_SZ + 1)];
    __syncthreads();
    float acc = 0.0f;
    for (int idx = t; idx < B_SZ * B_SZ; idx += 256) {
        int a = idx >> 7, b = idx & (B_SZ - 1);
        if (a != b) {
            float v = S[idx];
            acc += fmaxf(MARGIN + v - diag[a], 0.0f)
                 + fmaxf(MARGIN + v - diag[b], 0.0f);
        }
    }
    red[t] = acc;
    __syncthreads();
    for (int s = 128; s > 0; s >>= 1) {
        if (t < s) red[t] += red[t + s];
        __syncthreads();
    }
    if (t == 0) out[0] = red[0];
}

extern "C" void kernel_launch(void* const* d_in, const int* in_sizes, int n_in,
                              void* d_out, int out_size, void* d_ws, size_t ws_size,
                              hipStream_t stream) {
    const float* im  = (const float*)d_in[0];
    const float* s   = (const float*)d_in[1];
    const int*   s_l = (const int*)d_in[2];
    // d_in[3] (x) unused by the math

    const int n_im_pad = B_SZ * RP_SZ * D_SZ;   // 6,291,456
    const int n_s_pad  = B_SZ * WP_SZ * D_SZ;   // 8,388,608

    unsigned short* imb = (unsigned short*)d_ws;
    unsigned short* sb  = imb + n_im_pad;
    float* S = (float*)(sb + n_s_pad);          // 128*128 floats

    const int n4_total = (n_im_pad + n_s_pad) / 4;
    convert_pad_kernel<<<(n4_total + 255) / 256, 256, 0, stream>>>(im, s, imb, sb);

    scores_kernel<<<1024, 512, 0, stream>>>(imb, sb, s_l, S);

    loss_kernel<<<1, 256, 0, stream>>>(S, (float*)d_out);
}